// Round 2
// baseline (111.507 us; speedup 1.0000x reference)
//
#include <hip/hip_runtime.h>

typedef unsigned short ushort_t;
typedef __attribute__((ext_vector_type(4))) short short4_t;
typedef __attribute__((ext_vector_type(8))) short short8;
typedef __attribute__((ext_vector_type(4))) float floatx4;
typedef __attribute__((ext_vector_type(8))) __bf16 bf16x8;

__device__ __forceinline__ ushort_t f2b(float f) {
  union { float f; unsigned int i; } t; t.f = f;
  unsigned int u = t.i;
  return (ushort_t)((u + 0x7fffu + ((u >> 16) & 1u)) >> 16);  // RNE
}

__device__ __forceinline__ floatx4 mfma16(short8 a, short8 b, floatx4 c) {
  return __builtin_amdgcn_mfma_f32_16x16x32_bf16(
      __builtin_bit_cast(bf16x8, a), __builtin_bit_cast(bf16x8, b), c, 0, 0, 0);
}

__device__ __forceinline__ void gload16(const void* g, void* l) {
  __builtin_amdgcn_global_load_lds(
      (const __attribute__((address_space(1))) void*)g,
      (__attribute__((address_space(3))) void*)l, 16, 0, 0);
}

// ---------------------------------------------------------------------------
// f32 -> bf16 conversion, 8 elems/thread
// ---------------------------------------------------------------------------
__global__ __launch_bounds__(256) void k_f2b(
    const float* __restrict__ in, ushort_t* __restrict__ out, int n)
{
  int i = (blockIdx.x * 256 + threadIdx.x) * 8;
  if (i >= n) return;
  float4 a = *reinterpret_cast<const float4*>(in + i);
  float4 b = *reinterpret_cast<const float4*>(in + i + 4);
  short8 o;
  o[0] = (short)f2b(a.x); o[1] = (short)f2b(a.y);
  o[2] = (short)f2b(a.z); o[3] = (short)f2b(a.w);
  o[4] = (short)f2b(b.x); o[5] = (short)f2b(b.y);
  o[6] = (short)f2b(b.z); o[7] = (short)f2b(b.w);
  *reinterpret_cast<short8*>(out + i) = o;
}

// ---------------------------------------------------------------------------
// Kernel 1: P = softmax(attn_scores[0]) (bf16 out), and
//           R[h,s,:] = sum_k w_k(h,s) * rel_values[k,:]  (f32 out)
// One wave per (h,s) row. 4 waves/block. grid = 16*1024/4 = 4096.
// Input S is f32; 17 rel buckets collapse to prefix/suffix sums + 15 probs.
// ---------------------------------------------------------------------------
__global__ __launch_bounds__(256) void k_softmax_rel(
    const float* __restrict__ S, const float* __restrict__ relv,
    ushort_t* __restrict__ P, float* __restrict__ R)
{
  __shared__ float mid[4][16];  // 15 middle-bucket probs per wave
  const int wave = threadIdx.x >> 6, lane = threadIdx.x & 63;
  const int row = blockIdx.x * 4 + wave;   // h*1024 + s
  const int s = row & 1023;
  const float* src = S + (size_t)row * 1024;

  float v[4][4];
#pragma unroll
  for (int c = 0; c < 4; ++c) {
    float4 raw = *reinterpret_cast<const float4*>(src + c * 256 + lane * 4);
    v[c][0] = raw.x; v[c][1] = raw.y; v[c][2] = raw.z; v[c][3] = raw.w;
  }
  float m = -1e30f;
#pragma unroll
  for (int c = 0; c < 4; ++c)
#pragma unroll
    for (int e = 0; e < 4; ++e) m = fmaxf(m, v[c][e]);
#pragma unroll
  for (int d = 32; d; d >>= 1) m = fmaxf(m, __shfl_xor(m, d));

  float p[4][4];
  float tot = 0.f, sA = 0.f, sB = 0.f;   // sA: j<=s-8, sB: j>=s+8
#pragma unroll
  for (int c = 0; c < 4; ++c) {
#pragma unroll
    for (int e = 0; e < 4; ++e) {
      int j = c * 256 + lane * 4 + e;
      float pe = __expf(v[c][e] - m);
      p[c][e] = pe;
      tot += pe;
      sA += (j <= s - 8) ? pe : 0.f;
      sB += (j >= s + 8) ? pe : 0.f;
    }
  }
#pragma unroll
  for (int d = 32; d; d >>= 1) {
    tot += __shfl_xor(tot, d);
    sA  += __shfl_xor(sA, d);
    sB  += __shfl_xor(sB, d);
  }
  const float inv = 1.0f / tot;

  if (lane < 16) mid[wave][lane] = 0.f;
  __syncthreads();
#pragma unroll
  for (int c = 0; c < 4; ++c) {
#pragma unroll
    for (int e = 0; e < 4; ++e) {
      int j = c * 256 + lane * 4 + e;
      int tt = j - (s - 7);              // middle buckets: j in [s-7, s+7]
      if (tt >= 0 && tt < 15) mid[wave][tt] = p[c][e];
    }
  }
  __syncthreads();

  // R row: 64 head-dim outputs, one per lane
  float acc = sA * relv[lane] + sB * relv[16 * 64 + lane];
#pragma unroll
  for (int tt = 0; tt < 15; ++tt)
    acc += mid[wave][tt] * relv[(1 + tt) * 64 + lane];
  R[(size_t)row * 64 + lane] = acc * inv;

  // write normalized P (bf16, vectorized 8B)
#pragma unroll
  for (int c = 0; c < 4; ++c) {
    short4_t o;
#pragma unroll
    for (int e = 0; e < 4; ++e) o[e] = (short)f2b(p[c][e] * inv);
    *reinterpret_cast<short4_t*>(P + (size_t)row * 1024 + c * 256 + lane * 4) = o;
  }
}

// ---------------------------------------------------------------------------
// Kernels 2 & 4: C[M,N] = A[M,K] @ B[N,K]^T   (bf16 in, f32 acc)
// m97 structure: 128x128 tile, BK=32, 4 waves, global_load_lds width=16.
// OUTF32: write f32 C (final output) vs bf16 C (workspace).
// ---------------------------------------------------------------------------
template<bool OUTF32>
__global__ __launch_bounds__(256) void k_gemm_bt(
    const ushort_t* __restrict__ A, const ushort_t* __restrict__ B,
    void* __restrict__ Cv, int M, int N, int K)
{
  __shared__ ushort_t sA[128 * 32];
  __shared__ ushort_t sB[128 * 32];
  const int nbn = N >> 7;
  const int bm = blockIdx.x / nbn, bn = blockIdx.x % nbn;
  const int m0 = bm << 7, n0 = bn << 7;
  const int t = threadIdx.x, lane = t & 63, wave = t >> 6;
  const int wrow = (wave >> 1) << 6, wcol = (wave & 1) << 6;
  floatx4 acc[4][4] = {};

  const int srow = t >> 2;         // staging row within 64-row half
  const int scol = (t & 3) << 3;   // staging col (elements)

  for (int k0 = 0; k0 < K; k0 += 32) {
#pragma unroll
    for (int r = 0; r < 2; ++r) {
      int row = r * 64 + srow;
      gload16(A + (size_t)(m0 + row) * K + k0 + scol, (char*)sA + r * 4096 + t * 16);
      gload16(B + (size_t)(n0 + row) * K + k0 + scol, (char*)sB + r * 4096 + t * 16);
    }
    __syncthreads();
    short8 af[4], bf[4];
#pragma unroll
    for (int i = 0; i < 4; ++i)
      af[i] = *reinterpret_cast<const short8*>(
          &sA[(wrow + i * 16 + (lane & 15)) * 32 + (lane >> 4) * 8]);
#pragma unroll
    for (int j = 0; j < 4; ++j)
      bf[j] = *reinterpret_cast<const short8*>(
          &sB[(wcol + j * 16 + (lane & 15)) * 32 + (lane >> 4) * 8]);
#pragma unroll
    for (int i = 0; i < 4; ++i)
#pragma unroll
      for (int j = 0; j < 4; ++j)
        acc[i][j] = mfma16(af[i], bf[j], acc[i][j]);
    __syncthreads();
  }

  const int c16 = lane & 15, rg = lane >> 4;
#pragma unroll
  for (int i = 0; i < 4; ++i)
#pragma unroll
    for (int j = 0; j < 4; ++j) {
      int colg = n0 + wcol + j * 16 + c16;
#pragma unroll
      for (int r = 0; r < 4; ++r) {
        int rowg = m0 + wrow + i * 16 + rg * 4 + r;
        size_t idx = (size_t)rowg * N + colg;
        if constexpr (OUTF32) ((float*)Cv)[idx] = acc[i][j][r];
        else ((ushort_t*)Cv)[idx] = f2b(acc[i][j][r]);
      }
    }
}

// ---------------------------------------------------------------------------
// Kernel 3: per (b,h): O[b,s,h*64+d] = sum_j P[h,s,j]*Y[b,j,h*64+d] + R[h,s,d]
// Block = one (b,h,s-tile): 128 P-rows x 64 cols, K=1024 in BK=32 steps.
// Y tile reg-transposed into LDS [64][40] (80B stride, conflict-free b128).
// grid = 4*16*8 = 512.
// ---------------------------------------------------------------------------
__global__ __launch_bounds__(256) void k_head_pv(
    const ushort_t* __restrict__ P, const ushort_t* __restrict__ Y,
    const float* __restrict__ R, ushort_t* __restrict__ O)
{
  __shared__ ushort_t sP[128 * 32];
  __shared__ ushort_t sYt[64 * 40];
  const int id = blockIdx.x;
  const int st = id & 7, h = (id >> 3) & 15, b = id >> 7;
  const int s0 = st << 7;
  const ushort_t* Ph = P + (size_t)h * 1024 * 1024;
  const ushort_t* Yb = Y + (size_t)b * 1024 * 1024 + h * 64;
  const int t = threadIdx.x, lane = t & 63, wave = t >> 6;
  floatx4 acc[2][4] = {};

  const int srow = t >> 2, scol = (t & 3) << 3;
  const int ykk = t & 31, yn0 = (t >> 5) << 3;

  for (int k0 = 0; k0 < 1024; k0 += 32) {
#pragma unroll
    for (int r = 0; r < 2; ++r) {
      int row = r * 64 + srow;
      gload16(Ph + (size_t)(s0 + row) * 1024 + k0 + scol, (char*)sP + r * 4096 + t * 16);
    }
    // reg-transpose Y tile: thread t covers (k = k0+ykk, n = yn0..yn0+7)
    short8 yv = *reinterpret_cast<const short8*>(Yb + (size_t)(k0 + ykk) * 1024 + yn0);
#pragma unroll
    for (int j = 0; j < 8; ++j) sYt[(yn0 + j) * 40 + ykk] = (ushort_t)yv[j];
    __syncthreads();

    short8 bf[4];
#pragma unroll
    for (int j = 0; j < 4; ++j)
      bf[j] = *reinterpret_cast<const short8*>(
          &sYt[(j * 16 + (lane & 15)) * 40 + (lane >> 4) * 8]);
#pragma unroll
    for (int i = 0; i < 2; ++i) {
      short8 af = *reinterpret_cast<const short8*>(
          &sP[(wave * 32 + i * 16 + (lane & 15)) * 32 + (lane >> 4) * 8]);
#pragma unroll
      for (int j = 0; j < 4; ++j)
        acc[i][j] = mfma16(af, bf[j], acc[i][j]);
    }
    __syncthreads();
  }

  const int c16 = lane & 15, rg = lane >> 4;
#pragma unroll
  for (int i = 0; i < 2; ++i)
#pragma unroll
    for (int j = 0; j < 4; ++j) {
      int d = j * 16 + c16;
#pragma unroll
      for (int r = 0; r < 4; ++r) {
        int sr = s0 + wave * 32 + i * 16 + rg * 4 + r;
        float val = acc[i][j][r] + R[((size_t)h * 1024 + sr) * 64 + d];
        O[(size_t)b * 1048576 + (size_t)sr * 1024 + h * 64 + d] = f2b(val);
      }
    }
}

// ---------------------------------------------------------------------------
extern "C" void kernel_launch(void* const* d_in, const int* in_sizes, int n_in,
                              void* d_out, int out_size, void* d_ws, size_t ws_size,
                              hipStream_t stream)
{
  const float* x     = (const float*)d_in[0];  // (4,1024,1024) f32
  const float* W_in  = (const float*)d_in[1];  // (1024,1024)
  const float* W_out = (const float*)d_in[2];  // (1024,1024)
  const float* attn  = (const float*)d_in[3];  // (1,16,1024,1024)
  const float* relv  = (const float*)d_in[4];  // (17,64)
  float* out = (float*)d_out;                  // (4,1024,1024) f32

  char* ws = (char*)d_ws;
  // workspace layout (bytes)
  ushort_t* xb  = (ushort_t*)(ws);                    //  8 MB (4M bf16)
  ushort_t* Wib = (ushort_t*)(ws + (8u << 20));       //  2 MB
  ushort_t* Wob = (ushort_t*)(ws + (10u << 20));      //  2 MB
  ushort_t* P   = (ushort_t*)(ws + (12u << 20));      // 32 MB (16M bf16)
  float*    R   = (float*)   (ws + (44u << 20));      //  4 MB (1M f32)
  ushort_t* Y   = (ushort_t*)(ws + (48u << 20));      //  8 MB
  ushort_t* O   = (ushort_t*)(ws + (56u << 20));      //  8 MB  -> 64 MB total

  k_f2b<<<2048, 256, 0, stream>>>(x, xb, 4 * 1024 * 1024);
  k_f2b<<<512, 256, 0, stream>>>(W_in, Wib, 1024 * 1024);
  k_f2b<<<512, 256, 0, stream>>>(W_out, Wob, 1024 * 1024);
  k_softmax_rel<<<4096, 256, 0, stream>>>(attn, relv, P, R);
  k_gemm_bt<false><<<256, 256, 0, stream>>>(xb, Wib, Y, 4096, 1024, 1024);
  k_head_pv<<<512, 256, 0, stream>>>(P, Y, R, O);
  k_gemm_bt<true><<<256, 256, 0, stream>>>(O, Wob, out, 4096, 1024, 1024);
}

// Round 3
// 97.111 us; speedup vs baseline: 1.1482x; 1.1482x over previous
//
#include <hip/hip_runtime.h>

typedef unsigned short ushort_t;
typedef __attribute__((ext_vector_type(4))) short short4_t;
typedef __attribute__((ext_vector_type(8))) short short8;
typedef __attribute__((ext_vector_type(4))) float floatx4;
typedef __attribute__((ext_vector_type(8))) __bf16 bf16x8;

__device__ __forceinline__ ushort_t f2b(float f) {
  union { float f; unsigned int i; } t; t.f = f;
  unsigned int u = t.i;
  return (ushort_t)((u + 0x7fffu + ((u >> 16) & 1u)) >> 16);  // RNE
}

__device__ __forceinline__ floatx4 mfma16(short8 a, short8 b, floatx4 c) {
  return __builtin_amdgcn_mfma_f32_16x16x32_bf16(
      __builtin_bit_cast(bf16x8, a), __builtin_bit_cast(bf16x8, b), c, 0, 0, 0);
}

__device__ __forceinline__ void gload16(const void* g, void* l) {
  __builtin_amdgcn_global_load_lds(
      (const __attribute__((address_space(1))) void*)g,
      (__attribute__((address_space(3))) void*)l, 16, 0, 0);
}

// ---------------------------------------------------------------------------
// f32 -> bf16 conversion, 8 elems/thread
// ---------------------------------------------------------------------------
__global__ __launch_bounds__(256) void k_f2b(
    const float* __restrict__ in, ushort_t* __restrict__ out, int n)
{
  int i = (blockIdx.x * 256 + threadIdx.x) * 8;
  if (i >= n) return;
  float4 a = *reinterpret_cast<const float4*>(in + i);
  float4 b = *reinterpret_cast<const float4*>(in + i + 4);
  short8 o;
  o[0] = (short)f2b(a.x); o[1] = (short)f2b(a.y);
  o[2] = (short)f2b(a.z); o[3] = (short)f2b(a.w);
  o[4] = (short)f2b(b.x); o[5] = (short)f2b(b.y);
  o[6] = (short)f2b(b.z); o[7] = (short)f2b(b.w);
  *reinterpret_cast<short8*>(out + i) = o;
}

// ---------------------------------------------------------------------------
// Kernel: P = softmax(attn_scores[0]) (bf16), R[h,s,:] = rel-bucket mix (f32)
// One wave per (h,s) row. 4 waves/block. grid = 4096.
// ---------------------------------------------------------------------------
__global__ __launch_bounds__(256) void k_softmax_rel(
    const float* __restrict__ S, const float* __restrict__ relv,
    ushort_t* __restrict__ P, float* __restrict__ R)
{
  __shared__ float mid[4][16];
  const int wave = threadIdx.x >> 6, lane = threadIdx.x & 63;
  const int row = blockIdx.x * 4 + wave;   // h*1024 + s
  const int s = row & 1023;
  const float* src = S + (size_t)row * 1024;

  float v[4][4];
#pragma unroll
  for (int c = 0; c < 4; ++c) {
    float4 raw = *reinterpret_cast<const float4*>(src + c * 256 + lane * 4);
    v[c][0] = raw.x; v[c][1] = raw.y; v[c][2] = raw.z; v[c][3] = raw.w;
  }
  float m = -1e30f;
#pragma unroll
  for (int c = 0; c < 4; ++c)
#pragma unroll
    for (int e = 0; e < 4; ++e) m = fmaxf(m, v[c][e]);
#pragma unroll
  for (int d = 32; d; d >>= 1) m = fmaxf(m, __shfl_xor(m, d));

  float p[4][4];
  float tot = 0.f, sA = 0.f, sB = 0.f;
#pragma unroll
  for (int c = 0; c < 4; ++c) {
#pragma unroll
    for (int e = 0; e < 4; ++e) {
      int j = c * 256 + lane * 4 + e;
      float pe = __expf(v[c][e] - m);
      p[c][e] = pe;
      tot += pe;
      sA += (j <= s - 8) ? pe : 0.f;
      sB += (j >= s + 8) ? pe : 0.f;
    }
  }
#pragma unroll
  for (int d = 32; d; d >>= 1) {
    tot += __shfl_xor(tot, d);
    sA  += __shfl_xor(sA, d);
    sB  += __shfl_xor(sB, d);
  }
  const float inv = 1.0f / tot;

  if (lane < 16) mid[wave][lane] = 0.f;
  __syncthreads();
#pragma unroll
  for (int c = 0; c < 4; ++c) {
#pragma unroll
    for (int e = 0; e < 4; ++e) {
      int j = c * 256 + lane * 4 + e;
      int tt = j - (s - 7);
      if (tt >= 0 && tt < 15) mid[wave][tt] = p[c][e];
    }
  }
  __syncthreads();

  float acc = sA * relv[lane] + sB * relv[16 * 64 + lane];
#pragma unroll
  for (int tt = 0; tt < 15; ++tt)
    acc += mid[wave][tt] * relv[(1 + tt) * 64 + lane];
  R[(size_t)row * 64 + lane] = acc * inv;

#pragma unroll
  for (int c = 0; c < 4; ++c) {
    short4_t o;
#pragma unroll
    for (int e = 0; e < 4; ++e) o[e] = (short)f2b(p[c][e] * inv);
    *reinterpret_cast<short4_t*>(P + (size_t)row * 1024 + c * 256 + lane * 4) = o;
  }
}

// ---------------------------------------------------------------------------
// Shared 64x128-tile K-loop (BK=32, 4 waves, gload16 staging, bf16, f32 acc).
// C[m][n] = sum_k A0[m][k] * B0[n][k]; acc holds the wave's 32x64 sub-tile.
// ---------------------------------------------------------------------------
__device__ __forceinline__ void gemm_loop64x128(
    const ushort_t* __restrict__ A0, const ushort_t* __restrict__ B0, int K,
    ushort_t* sA, ushort_t* sB, floatx4 (&acc)[2][4])
{
  const int t = threadIdx.x, lane = t & 63, wave = t >> 6;
  const int wr = (wave >> 1) << 5, wc = (wave & 1) << 6;
  const int srow = t >> 2, scol = (t & 3) << 3;

  for (int k0 = 0; k0 < K; k0 += 32) {
    gload16(A0 + (size_t)srow * K + k0 + scol, (char*)sA + t * 16);
    gload16(B0 + (size_t)srow * K + k0 + scol, (char*)sB + t * 16);
    gload16(B0 + (size_t)(64 + srow) * K + k0 + scol, (char*)sB + 4096 + t * 16);
    __syncthreads();
    short8 af[2], bf[4];
#pragma unroll
    for (int i = 0; i < 2; ++i)
      af[i] = *reinterpret_cast<const short8*>(
          &sA[(wr + i * 16 + (lane & 15)) * 32 + (lane >> 4) * 8]);
#pragma unroll
    for (int j = 0; j < 4; ++j)
      bf[j] = *reinterpret_cast<const short8*>(
          &sB[(wc + j * 16 + (lane & 15)) * 32 + (lane >> 4) * 8]);
#pragma unroll
    for (int i = 0; i < 2; ++i)
#pragma unroll
      for (int j = 0; j < 4; ++j)
        acc[i][j] = mfma16(af[i], bf[j], acc[i][j]);
    __syncthreads();
  }
}

// ---------------------------------------------------------------------------
// GEMM 1: Yt[h][b][d][s] = sum_k W_in[h*64+d][k] * x[b*1024+s][k]
// A-side = W_in rows (1024), B-side = x rows (4096). grid = 16*32 = 512.
// ---------------------------------------------------------------------------
__global__ __launch_bounds__(256) void k_gemm_xw(
    const ushort_t* __restrict__ W, const ushort_t* __restrict__ X,
    ushort_t* __restrict__ Yt)
{
  __shared__ ushort_t sA[64 * 32];
  __shared__ ushort_t sB[128 * 32];
  const int m0 = (blockIdx.x & 15) << 6, n0 = (blockIdx.x >> 4) << 7;
  floatx4 acc[2][4] = {};
  gemm_loop64x128(W + (size_t)m0 * 1024, X + (size_t)n0 * 1024, 1024, sA, sB, acc);

  const int lane = threadIdx.x & 63, wave = threadIdx.x >> 6;
  const int wr = (wave >> 1) << 5, wc = (wave & 1) << 6;
  const int c16 = lane & 15, rg = lane >> 4;
#pragma unroll
  for (int i = 0; i < 2; ++i)
#pragma unroll
    for (int j = 0; j < 4; ++j)
#pragma unroll
      for (int r = 0; r < 4; ++r) {
        int wrow = m0 + wr + i * 16 + rg * 4 + r;   // = h*64 + d
        int col  = n0 + wc + j * 16 + c16;          // = b*1024 + s
        int h = wrow >> 6, d = wrow & 63;
        int b = col >> 10, s = col & 1023;
        Yt[(((size_t)(h * 4 + b) << 6) + d) * 1024 + s] = f2b(acc[i][j][r]);
      }
}

// ---------------------------------------------------------------------------
// GEMM 2 (PV): O[b][s][h*64+d] = sum_j P[h][s][j] * Yt[h][b][d][j] + R[h][s][d]
// Per h: M=1024 (P rows), N=256 (b,d), K=1024. grid = 16*32 = 512.
// ---------------------------------------------------------------------------
__global__ __launch_bounds__(256) void k_head_pv2(
    const ushort_t* __restrict__ P, const ushort_t* __restrict__ Yt,
    const float* __restrict__ R, ushort_t* __restrict__ O)
{
  __shared__ ushort_t sA[64 * 32];
  __shared__ ushort_t sB[128 * 32];
  const int h = blockIdx.x >> 5, r5 = blockIdx.x & 31;
  const int m0 = (r5 >> 1) << 6, n0 = (r5 & 1) << 7;
  floatx4 acc[2][4] = {};
  gemm_loop64x128(P + ((size_t)h << 20) + (size_t)m0 * 1024,
                  Yt + ((size_t)h << 18) + (size_t)n0 * 1024, 1024, sA, sB, acc);

  const int lane = threadIdx.x & 63, wave = threadIdx.x >> 6;
  const int wr = (wave >> 1) << 5, wc = (wave & 1) << 6;
  const int c16 = lane & 15, rg = lane >> 4;
#pragma unroll
  for (int i = 0; i < 2; ++i)
#pragma unroll
    for (int j = 0; j < 4; ++j)
#pragma unroll
      for (int r = 0; r < 4; ++r) {
        int sr = m0 + wr + i * 16 + rg * 4 + r;
        int c  = n0 + wc + j * 16 + c16;            // = b*64 + d
        int b = c >> 6, d = c & 63;
        float val = acc[i][j][r] + R[(((size_t)h << 10) + sr) * 64 + d];
        O[((size_t)b << 20) + (size_t)sr * 1024 + (h << 6) + d] = f2b(val);
      }
}

// ---------------------------------------------------------------------------
// GEMM 3: out[m][n] = sum_k O[m][k] * W_out[n][k]  (f32 out). grid = 64*8=512.
// ---------------------------------------------------------------------------
__global__ __launch_bounds__(256) void k_gemm_out(
    const ushort_t* __restrict__ A, const ushort_t* __restrict__ B,
    float* __restrict__ C)
{
  __shared__ ushort_t sA[64 * 32];
  __shared__ ushort_t sB[128 * 32];
  const int m0 = (blockIdx.x >> 3) << 6, n0 = (blockIdx.x & 7) << 7;
  floatx4 acc[2][4] = {};
  gemm_loop64x128(A + (size_t)m0 * 1024, B + (size_t)n0 * 1024, 1024, sA, sB, acc);

  const int lane = threadIdx.x & 63, wave = threadIdx.x >> 6;
  const int wr = (wave >> 1) << 5, wc = (wave & 1) << 6;
  const int c16 = lane & 15, rg = lane >> 4;
#pragma unroll
  for (int i = 0; i < 2; ++i)
#pragma unroll
    for (int j = 0; j < 4; ++j)
#pragma unroll
      for (int r = 0; r < 4; ++r) {
        int rowg = m0 + wr + i * 16 + rg * 4 + r;
        int colg = n0 + wc + j * 16 + c16;
        C[(size_t)rowg * 1024 + colg] = acc[i][j][r];
      }
}

// ---------------------------------------------------------------------------
extern "C" void kernel_launch(void* const* d_in, const int* in_sizes, int n_in,
                              void* d_out, int out_size, void* d_ws, size_t ws_size,
                              hipStream_t stream)
{
  const float* x     = (const float*)d_in[0];
  const float* W_in  = (const float*)d_in[1];
  const float* W_out = (const float*)d_in[2];
  const float* attn  = (const float*)d_in[3];
  const float* relv  = (const float*)d_in[4];
  float* out = (float*)d_out;

  char* ws = (char*)d_ws;
  ushort_t* xb  = (ushort_t*)(ws);                //  8 MB
  ushort_t* Wib = (ushort_t*)(ws + (8u << 20));   //  2 MB
  ushort_t* Wob = (ushort_t*)(ws + (10u << 20));  //  2 MB
  ushort_t* P   = (ushort_t*)(ws + (12u << 20));  // 32 MB
  float*    R   = (float*)   (ws + (44u << 20));  //  4 MB
  ushort_t* Yt  = (ushort_t*)(ws + (48u << 20));  //  8 MB  [h][b][d][s]
  ushort_t* O   = (ushort_t*)(ws + (56u << 20));  //  8 MB  [b][s][h*64+d]

  k_f2b<<<2048, 256, 0, stream>>>(x, xb, 4 * 1024 * 1024);
  k_f2b<<<512, 256, 0, stream>>>(W_in, Wib, 1024 * 1024);
  k_f2b<<<512, 256, 0, stream>>>(W_out, Wob, 1024 * 1024);
  k_softmax_rel<<<4096, 256, 0, stream>>>(attn, relv, P, R);
  k_gemm_xw<<<512, 256, 0, stream>>>(Wib, xb, Yt);
  k_head_pv2<<<512, 256, 0, stream>>>(P, Yt, R, O);
  k_gemm_out<<<512, 256, 0, stream>>>(O, Wob, out);
}

// Round 4
// 91.539 us; speedup vs baseline: 1.2181x; 1.0609x over previous
//
#include <hip/hip_runtime.h>

typedef unsigned short ushort_t;
typedef __attribute__((ext_vector_type(4))) short short4_t;
typedef __attribute__((ext_vector_type(8))) short short8;
typedef __attribute__((ext_vector_type(4))) float floatx4;
typedef __attribute__((ext_vector_type(8))) __bf16 bf16x8;

__device__ __forceinline__ ushort_t f2b(float f) {
  union { float f; unsigned int i; } t; t.f = f;
  unsigned int u = t.i;
  return (ushort_t)((u + 0x7fffu + ((u >> 16) & 1u)) >> 16);  // RNE
}

__device__ __forceinline__ floatx4 mfma16(short8 a, short8 b, floatx4 c) {
  return __builtin_amdgcn_mfma_f32_16x16x32_bf16(
      __builtin_bit_cast(bf16x8, a), __builtin_bit_cast(bf16x8, b), c, 0, 0, 0);
}

__device__ __forceinline__ void gload16(const void* g, void* l) {
  __builtin_amdgcn_global_load_lds(
      (const __attribute__((address_space(1))) void*)g,
      (__attribute__((address_space(3))) void*)l, 16, 0, 0);
}

// ---------------------------------------------------------------------------
// f32 -> bf16 conversion for x (4M), W_in (1M), W_out (1M) in one launch.
// 8 elems/thread. grid = 2048 + 512 + 512 = 3072.
// ---------------------------------------------------------------------------
__global__ __launch_bounds__(256) void k_f2b_all(
    const float* __restrict__ x, const float* __restrict__ Wi,
    const float* __restrict__ Wo, ushort_t* __restrict__ xb,
    ushort_t* __restrict__ Wib, ushort_t* __restrict__ Wob)
{
  const float* in; ushort_t* out; int i;
  if (blockIdx.x < 2048)      { in = x;  out = xb;  i = (blockIdx.x * 256 + threadIdx.x) * 8; }
  else if (blockIdx.x < 2560) { in = Wi; out = Wib; i = ((blockIdx.x - 2048) * 256 + threadIdx.x) * 8; }
  else                        { in = Wo; out = Wob; i = ((blockIdx.x - 2560) * 256 + threadIdx.x) * 8; }
  float4 a = *reinterpret_cast<const float4*>(in + i);
  float4 b = *reinterpret_cast<const float4*>(in + i + 4);
  short8 o;
  o[0] = (short)f2b(a.x); o[1] = (short)f2b(a.y);
  o[2] = (short)f2b(a.z); o[3] = (short)f2b(a.w);
  o[4] = (short)f2b(b.x); o[5] = (short)f2b(b.y);
  o[6] = (short)f2b(b.z); o[7] = (short)f2b(b.w);
  *reinterpret_cast<short8*>(out + i) = o;
}

// ---------------------------------------------------------------------------
// P = softmax(attn_scores[0]) (bf16), R[h,s,:] = rel-bucket mix (f32)
// One wave per (h,s) row. 4 waves/block. grid = 4096.
// ---------------------------------------------------------------------------
__global__ __launch_bounds__(256) void k_softmax_rel(
    const float* __restrict__ S, const float* __restrict__ relv,
    ushort_t* __restrict__ P, float* __restrict__ R)
{
  __shared__ float mid[4][16];
  const int wave = threadIdx.x >> 6, lane = threadIdx.x & 63;
  const int row = blockIdx.x * 4 + wave;   // h*1024 + s
  const int s = row & 1023;
  const float* src = S + (size_t)row * 1024;

  float v[4][4];
#pragma unroll
  for (int c = 0; c < 4; ++c) {
    float4 raw = *reinterpret_cast<const float4*>(src + c * 256 + lane * 4);
    v[c][0] = raw.x; v[c][1] = raw.y; v[c][2] = raw.z; v[c][3] = raw.w;
  }
  float m = -1e30f;
#pragma unroll
  for (int c = 0; c < 4; ++c)
#pragma unroll
    for (int e = 0; e < 4; ++e) m = fmaxf(m, v[c][e]);
#pragma unroll
  for (int d = 32; d; d >>= 1) m = fmaxf(m, __shfl_xor(m, d));

  float p[4][4];
  float tot = 0.f, sA = 0.f, sB = 0.f;
#pragma unroll
  for (int c = 0; c < 4; ++c) {
#pragma unroll
    for (int e = 0; e < 4; ++e) {
      int j = c * 256 + lane * 4 + e;
      float pe = __expf(v[c][e] - m);
      p[c][e] = pe;
      tot += pe;
      sA += (j <= s - 8) ? pe : 0.f;
      sB += (j >= s + 8) ? pe : 0.f;
    }
  }
#pragma unroll
  for (int d = 32; d; d >>= 1) {
    tot += __shfl_xor(tot, d);
    sA  += __shfl_xor(sA, d);
    sB  += __shfl_xor(sB, d);
  }
  const float inv = 1.0f / tot;

  if (lane < 16) mid[wave][lane] = 0.f;
  __syncthreads();
#pragma unroll
  for (int c = 0; c < 4; ++c) {
#pragma unroll
    for (int e = 0; e < 4; ++e) {
      int j = c * 256 + lane * 4 + e;
      int tt = j - (s - 7);
      if (tt >= 0 && tt < 15) mid[wave][tt] = p[c][e];
    }
  }
  __syncthreads();

  float acc = sA * relv[lane] + sB * relv[16 * 64 + lane];
#pragma unroll
  for (int tt = 0; tt < 15; ++tt)
    acc += mid[wave][tt] * relv[(1 + tt) * 64 + lane];
  R[(size_t)row * 64 + lane] = acc * inv;

#pragma unroll
  for (int c = 0; c < 4; ++c) {
    short4_t o;
#pragma unroll
    for (int e = 0; e < 4; ++e) o[e] = (short)f2b(p[c][e] * inv);
    *reinterpret_cast<short4_t*>(P + (size_t)row * 1024 + c * 256 + lane * 4) = o;
  }
}

// ---------------------------------------------------------------------------
// Depth-2 pipelined 64x128-tile K-loop. BK=32, 4 waves.
// 4 LDS buffers; STAGE(t+2) each iter; s_waitcnt vmcnt(6) (3 loads/stage x 2
// stages in flight); ONE raw s_barrier per K-step. Buffer staged at t is
// read at t, re-staged at t+6 (>=2 barriers later) -> no trailing barrier.
// sA: 4 x 64*32 elems (16 KB), sB: 4 x 128*32 elems (32 KB).
// ---------------------------------------------------------------------------
__device__ __forceinline__ void gemm_loop_pipe(
    const ushort_t* __restrict__ A0, const ushort_t* __restrict__ B0, int K,
    ushort_t* sA, ushort_t* sB, floatx4 (&acc)[2][4])
{
  const int t = threadIdx.x, lane = t & 63, wave = t >> 6;
  const int wr = (wave >> 1) << 5, wc = (wave & 1) << 6;
  const int srow = t >> 2, scol = (t & 3) << 3;
  const int nk = K >> 5;

#define STAGE(kt, buf)                                                          \
  {                                                                             \
    int k0 = (kt) << 5;                                                         \
    gload16(A0 + (size_t)srow * K + k0 + scol, (char*)sA + (buf) * 4096 + t * 16); \
    gload16(B0 + (size_t)srow * K + k0 + scol, (char*)sB + (buf) * 8192 + t * 16); \
    gload16(B0 + (size_t)(64 + srow) * K + k0 + scol,                           \
            (char*)sB + (buf) * 8192 + 4096 + t * 16);                          \
  }

  STAGE(0, 0);
  STAGE(1, 1);
  for (int kt = 0; kt < nk; ++kt) {
    const int buf = kt & 3;
    if (kt + 2 < nk) {
      STAGE(kt + 2, (kt + 2) & 3);
      asm volatile("s_waitcnt vmcnt(6)" ::: "memory");
    } else if (kt + 1 < nk) {
      asm volatile("s_waitcnt vmcnt(3)" ::: "memory");
    } else {
      asm volatile("s_waitcnt vmcnt(0)" ::: "memory");
    }
    __builtin_amdgcn_s_barrier();

    const ushort_t* bA = sA + buf * 2048;
    const ushort_t* bB = sB + buf * 4096;
    short8 af[2], bf[4];
#pragma unroll
    for (int i = 0; i < 2; ++i)
      af[i] = *reinterpret_cast<const short8*>(
          &bA[(wr + i * 16 + (lane & 15)) * 32 + (lane >> 4) * 8]);
#pragma unroll
    for (int j = 0; j < 4; ++j)
      bf[j] = *reinterpret_cast<const short8*>(
          &bB[(wc + j * 16 + (lane & 15)) * 32 + (lane >> 4) * 8]);
    __builtin_amdgcn_s_setprio(1);
#pragma unroll
    for (int i = 0; i < 2; ++i)
#pragma unroll
      for (int j = 0; j < 4; ++j)
        acc[i][j] = mfma16(af[i], bf[j], acc[i][j]);
    __builtin_amdgcn_s_setprio(0);
  }
#undef STAGE
}

// ---------------------------------------------------------------------------
// GEMM 1: Yt[h][b][d][s] = sum_k W_in[h*64+d][k] * x[b*1024+s][k]
// grid = 16 m-tiles x 32 n-tiles = 512.
// ---------------------------------------------------------------------------
__global__ __launch_bounds__(256) void k_gemm_xw(
    const ushort_t* __restrict__ W, const ushort_t* __restrict__ X,
    ushort_t* __restrict__ Yt)
{
  __shared__ ushort_t sA[4 * 64 * 32];
  __shared__ ushort_t sB[4 * 128 * 32];
  const int m0 = (blockIdx.x & 15) << 6, n0 = (blockIdx.x >> 4) << 7;
  floatx4 acc[2][4] = {};
  gemm_loop_pipe(W + (size_t)m0 * 1024, X + (size_t)n0 * 1024, 1024, sA, sB, acc);

  const int lane = threadIdx.x & 63, wave = threadIdx.x >> 6;
  const int wr = (wave >> 1) << 5, wc = (wave & 1) << 6;
  const int c16 = lane & 15, rg = lane >> 4;
#pragma unroll
  for (int i = 0; i < 2; ++i)
#pragma unroll
    for (int j = 0; j < 4; ++j)
#pragma unroll
      for (int r = 0; r < 4; ++r) {
        int wrow = m0 + wr + i * 16 + rg * 4 + r;   // = h*64 + d
        int col  = n0 + wc + j * 16 + c16;          // = b*1024 + s
        int h = wrow >> 6, d = wrow & 63;
        int b = col >> 10, s = col & 1023;
        Yt[(((size_t)(h * 4 + b) << 6) + d) * 1024 + s] = f2b(acc[i][j][r]);
      }
}

// ---------------------------------------------------------------------------
// GEMM 2 (PV): O[b][s][h*64+d] = sum_j P[h][s][j]*Yt[h][b][d][j] + R[h][s][d]
// Per h: M=1024 (16 m-tiles), N=256 (2 n-tiles). grid = 512.
// ---------------------------------------------------------------------------
__global__ __launch_bounds__(256) void k_head_pv2(
    const ushort_t* __restrict__ P, const ushort_t* __restrict__ Yt,
    const float* __restrict__ R, ushort_t* __restrict__ O)
{
  __shared__ ushort_t sA[4 * 64 * 32];
  __shared__ ushort_t sB[4 * 128 * 32];
  const int h = blockIdx.x >> 5, r5 = blockIdx.x & 31;
  const int m0 = (r5 >> 1) << 6, n0 = (r5 & 1) << 7;
  floatx4 acc[2][4] = {};
  gemm_loop_pipe(P + ((size_t)h << 20) + (size_t)m0 * 1024,
                 Yt + ((size_t)h << 18) + (size_t)n0 * 1024, 1024, sA, sB, acc);

  const int lane = threadIdx.x & 63, wave = threadIdx.x >> 6;
  const int wr = (wave >> 1) << 5, wc = (wave & 1) << 6;
  const int c16 = lane & 15, rg = lane >> 4;
#pragma unroll
  for (int i = 0; i < 2; ++i)
#pragma unroll
    for (int j = 0; j < 4; ++j)
#pragma unroll
      for (int r = 0; r < 4; ++r) {
        int sr = m0 + wr + i * 16 + rg * 4 + r;
        int c  = n0 + wc + j * 16 + c16;            // = b*64 + d
        int b = c >> 6, d = c & 63;
        float val = acc[i][j][r] + R[(((size_t)h << 10) + sr) * 64 + d];
        O[((size_t)b << 20) + (size_t)sr * 1024 + (h << 6) + d] = f2b(val);
      }
}

// ---------------------------------------------------------------------------
// GEMM 3: out[m][n] = sum_k O[m][k] * W_out[n][k]  (f32 out). grid = 512.
// ---------------------------------------------------------------------------
__global__ __launch_bounds__(256) void k_gemm_out(
    const ushort_t* __restrict__ A, const ushort_t* __restrict__ B,
    float* __restrict__ C)
{
  __shared__ ushort_t sA[4 * 64 * 32];
  __shared__ ushort_t sB[4 * 128 * 32];
  const int m0 = (blockIdx.x >> 3) << 6, n0 = (blockIdx.x & 7) << 7;
  floatx4 acc[2][4] = {};
  gemm_loop_pipe(A + (size_t)m0 * 1024, B + (size_t)n0 * 1024, 1024, sA, sB, acc);

  const int lane = threadIdx.x & 63, wave = threadIdx.x >> 6;
  const int wr = (wave >> 1) << 5, wc = (wave & 1) << 6;
  const int c16 = lane & 15, rg = lane >> 4;
#pragma unroll
  for (int i = 0; i < 2; ++i)
#pragma unroll
    for (int j = 0; j < 4; ++j)
#pragma unroll
      for (int r = 0; r < 4; ++r) {
        int rowg = m0 + wr + i * 16 + rg * 4 + r;
        int colg = n0 + wc + j * 16 + c16;
        C[(size_t)rowg * 1024 + colg] = acc[i][j][r];
      }
}

// ---------------------------------------------------------------------------
extern "C" void kernel_launch(void* const* d_in, const int* in_sizes, int n_in,
                              void* d_out, int out_size, void* d_ws, size_t ws_size,
                              hipStream_t stream)
{
  const float* x     = (const float*)d_in[0];
  const float* W_in  = (const float*)d_in[1];
  const float* W_out = (const float*)d_in[2];
  const float* attn  = (const float*)d_in[3];
  const float* relv  = (const float*)d_in[4];
  float* out = (float*)d_out;

  char* ws = (char*)d_ws;
  ushort_t* xb  = (ushort_t*)(ws);                //  8 MB
  ushort_t* Wib = (ushort_t*)(ws + (8u << 20));   //  2 MB
  ushort_t* Wob = (ushort_t*)(ws + (10u << 20));  //  2 MB
  ushort_t* P   = (ushort_t*)(ws + (12u << 20));  // 32 MB
  float*    R   = (float*)   (ws + (44u << 20));  //  4 MB
  ushort_t* Yt  = (ushort_t*)(ws + (48u << 20));  //  8 MB  [h][b][d][s]
  ushort_t* O   = (ushort_t*)(ws + (56u << 20));  //  8 MB  [b][s][h*64+d]

  k_f2b_all<<<3072, 256, 0, stream>>>(x, W_in, W_out, xb, Wib, Wob);
  k_softmax_rel<<<4096, 256, 0, stream>>>(attn, relv, P, R);
  k_gemm_xw<<<512, 256, 0, stream>>>(Wib, xb, Yt);
  k_head_pv2<<<512, 256, 0, stream>>>(P, Yt, R, O);
  k_gemm_out<<<512, 256, 0, stream>>>(O, Wob, out);
}